// Round 12
// baseline (135.085 us; speedup 1.0000x reference)
//
#include <hip/hip_runtime.h>
#include <math.h>

constexpr int B = 16, F = 64, E = 16, H = 64, W = 64;
constexpr int XP = 66;          // padded x dim (1 zero col each side)
constexpr int CP = 72;          // s_in/sxo inner pad (16B-aligned bf16x8 rows)
constexpr int SPP = 68;         // s_sp inner pad (bf16)
constexpr int YSTRIDE = XP * F; // 4224 elems per (b,y) row in xTs

typedef __bf16 bf16x8 __attribute__((ext_vector_type(8)));
typedef __bf16 bf16x4 __attribute__((ext_vector_type(4)));
typedef float f32x16 __attribute__((ext_vector_type(16)));
typedef float f32x4 __attribute__((ext_vector_type(4)));

// ---------------------------------------------------------------------------
// prep: blk<1024: transpose state -> xTs[b][y][x+1][c] bf16 (borders zeroed)
//       blk<1168: repack weights (wA1[o][t*64+c], wA2[e][t*64+c], wT3b=bf16(c3_w))
//       else    : zero d_out[0..16383] (the (B,E,F) accumulator region)
// ---------------------------------------------------------------------------
__global__ __launch_bounds__(256) void prep_kernel(
    const float* __restrict__ state, const float* __restrict__ pre_w,
    const float* __restrict__ attn_w, const float* __restrict__ c3_w,
    __bf16* __restrict__ xTs, __bf16* __restrict__ wA1,
    __bf16* __restrict__ wA2, __bf16* __restrict__ wT3b,
    float* __restrict__ out0)
{
    __shared__ float s_t[64][68];
    const int blk = blockIdx.x;
    const int tid = threadIdx.x;

    if (blk < 1024) {
        const int b = blk >> 6, y = blk & 63;
        {
            int c = tid >> 2, x0 = (tid & 3) * 16;
            const float* src = state + ((size_t)(b * F + c) * H + y) * W + x0;
            #pragma unroll
            for (int q = 0; q < 4; ++q)
                *(float4*)&s_t[c][x0 + 4 * q] = *(const float4*)(src + 4 * q);
        }
        __syncthreads();
        __bf16* dst = xTs + (size_t)(b * H + y) * YSTRIDE;
        #pragma unroll
        for (int i = 0; i < 2; ++i) {
            int t = tid + i * 256;
            int x = t >> 3, cg = t & 7;
            bf16x8 v;
            #pragma unroll
            for (int j = 0; j < 8; ++j) v[j] = (__bf16)s_t[cg * 8 + j][x];
            *(bf16x8*)(dst + (x + 1) * F + cg * 8) = v;
        }
        if (tid < 16) {
            int bd = tid >> 3, cg = tid & 7;
            bf16x8 z = {};
            *(bf16x8*)(dst + (bd ? 65 : 0) * F + cg * 8) = z;
        }
    } else if (blk < 1168) {
        int idx = (blk - 1024) * 256 + tid;
        if (idx < 64 * 576) {
            int o = idx / 576, rem = idx - o * 576, t = rem >> 6, c = rem & 63;
            wA1[idx] = (__bf16)pre_w[(o * 64 + c) * 9 + t];
        }
        if (idx < 16 * 576) {
            int e = idx / 576, rem = idx - e * 576, t = rem >> 6, c = rem & 63;
            wA2[idx] = (__bf16)attn_w[(e * 64 + c) * 9 + t];
        }
        if (idx < 64 * 64) {
            wT3b[idx] = (__bf16)c3_w[idx];   // already [o][f] row-major
        }
    } else {
        int idx = (blk - 1168) * 256 + tid;  // 16 blocks cover 16384 floats
        float4 z = {0.f, 0.f, 0.f, 0.f};
        *(float4*)(out0 + idx * 4) = z;
    }
}

// ---------------------------------------------------------------------------
// mega v6: 512 threads (8 waves), __launch_bounds__(512,2) -> 16 waves/CU,
// VGPR cap 128 (no spills, unlike R9's 64-cap). 4 barriers:
//  stage | B1 | conv1 (wave=(r1,nt), M64xN32) + sproj (wave=(mt,nt,rr)) | B2 |
//  epilogues -> sxo + s_sp + borders | B3 | conv2 (wave=(rw,xq)) | B4 |
//  reduce (thread=(o,eg,rr)) -> atomicAdd.
// ---------------------------------------------------------------------------
__global__ __launch_bounds__(512, 2) void mega_kernel(
    const __bf16* __restrict__ xTs, const __bf16* __restrict__ wA1,
    const __bf16* __restrict__ wA2, const __bf16* __restrict__ wT3b,
    const float* __restrict__ pre_b, const float* __restrict__ attn_b,
    const float* __restrict__ c3_b,
    float* __restrict__ attn_out, float* __restrict__ out)
{
    __shared__ __align__(16) char smem[63616];
    const int b = blockIdx.y, yp = blockIdx.x;
    const int tid = threadIdx.x;
    const int wave = tid >> 6, lane = tid & 63;
    const int y0 = yp * 2;

    __bf16* s_in = (__bf16*)smem;                        // [6][XP][CP] 57024 B
    __bf16* sxo  = (__bf16*)smem;                        // [4][XP][CP] 38016 B (overlay)
    __bf16* s_sp = (__bf16*)(smem + 38016);              // [2][64][SPP] 17408 B
    float (*s_attn)[64][16] = (float(*)[64][16])(smem + 55424);  // 8192 B

    // ---------- stage 6 input rows (coalesced; OOB rows zero) ----------
    for (int t = tid; t < 6 * XP * 8; t += 512) {
        int r = t / (XP * 8), rem = t - r * (XP * 8);
        int x = rem >> 3, cg = rem & 7;
        int yy = y0 - 2 + r;
        bf16x8 v = {};
        if (yy >= 0 && yy < H)
            v = *(const bf16x8*)(xTs + (size_t)(b * H + yy) * YSTRIDE + x * F + cg * 8);
        *(bf16x8*)(s_in + (r * XP + x) * CP + cg * 8) = v;
    }
    __syncthreads();   // B1

    const int n = lane & 31, kh = lane >> 5;

    // ---------- sproj fragment preload: wave = (mt_s, nt_s, rr_s) ----------
    const int mt_s = wave & 1, nt_s = (wave >> 1) & 1, rr_s = wave >> 2;
    bf16x8 spA[4], spB[4];
    #pragma unroll
    for (int cq = 0; cq < 4; ++cq) {
        spA[cq] = *(const bf16x8*)(wT3b + (mt_s * 32 + n) * 64 + kh * 8 + cq * 16);
        spB[cq] = *(const bf16x8*)(xTs + (size_t)(b * H + y0 + rr_s) * YSTRIDE
                                   + (nt_s * 32 + n + 1) * F + kh * 8 + cq * 16);
    }

    // ---------- conv1: wave = (r1, nt1); output row yr = y0-1+r1, x-half nt1 --
    const int r1 = wave >> 1, nt1 = wave & 1;
    const int yr = y0 - 1 + r1;
    const bool valid = (yr >= 0 && yr < H);
    f32x16 acc0 = {}, acc1 = {};   // mt=0 / mt=1 output-channel tiles
    if (valid) {
        #pragma unroll
        for (int dy = 0; dy < 3; ++dy) {
            // input row in s_in: (yr-1+dy) - (y0-2) = r1 + dy
            #pragma unroll
            for (int dx = 0; dx < 3; ++dx) {
                const int t9 = dy * 3 + dx;
                const __bf16* bB = s_in + ((r1 + dy) * XP + (nt1 * 32 + n + dx)) * CP + kh * 8;
                #pragma unroll
                for (int cq = 0; cq < 4; ++cq) {
                    const int ko = cq * 16 + kh * 8;
                    bf16x8 a0 = *(const bf16x8*)(wA1 + n * 576 + t9 * 64 + ko);
                    bf16x8 a1 = *(const bf16x8*)(wA1 + (32 + n) * 576 + t9 * 64 + ko);
                    bf16x8 bb = *(const bf16x8*)(bB + cq * 16);
                    acc0 = __builtin_amdgcn_mfma_f32_32x32x16_bf16(a0, bb, acc0, 0, 0, 0);
                    acc1 = __builtin_amdgcn_mfma_f32_32x32x16_bf16(a1, bb, acc1, 0, 0, 0);
                }
            }
        }
    }

    // ---------- sproj MFMAs (fragments long since arrived) ----------
    f32x16 accsp = {};
    #pragma unroll
    for (int cq = 0; cq < 4; ++cq)
        accsp = __builtin_amdgcn_mfma_f32_32x32x16_bf16(spA[cq], spB[cq], accsp, 0, 0, 0);

    __syncthreads();   // B2: all s_in reads done; overlays writable

    // ---------- conv1 epilogue -> sxo; sproj epilogue -> s_sp ----------
    {
        __bf16* orow = sxo + r1 * XP * CP;
        #pragma unroll
        for (int g = 0; g < 4; ++g) {
            int o0 = kh * 4 + g * 8;
            f32x4 b40 = *(const f32x4*)(pre_b + o0);
            f32x4 b41 = *(const f32x4*)(pre_b + 32 + o0);
            bf16x4 v0 = {}, v1 = {};
            if (valid) {
                #pragma unroll
                for (int r = 0; r < 4; ++r) {
                    v0[r] = (__bf16)fmaxf(acc0[g * 4 + r] + b40[r], 0.f);
                    v1[r] = (__bf16)fmaxf(acc1[g * 4 + r] + b41[r], 0.f);
                }
            }
            *(bf16x4*)(orow + (nt1 * 32 + n + 1) * CP + o0) = v0;
            *(bf16x4*)(orow + (nt1 * 32 + n + 1) * CP + 32 + o0) = v1;
        }
        // sproj: D row o = mt_s*32+kh*4+g*8+r, col p = nt_s*32+n
        const int p = nt_s * 32 + n;
        #pragma unroll
        for (int g = 0; g < 4; ++g)
            #pragma unroll
            for (int r = 0; r < 4; ++r) {
                int o = mt_s * 32 + kh * 4 + g * 8 + r;
                s_sp[(rr_s * 64 + o) * SPP + p] = (__bf16)accsp[g * 4 + r];
            }
        if (tid < 64) {   // zero x-borders (cols 0 and 65) of all 4 sxo rows
            int r = tid >> 4, bd = (tid >> 3) & 1, cg = tid & 7;
            bf16x8 z = {};
            *(bf16x8*)(sxo + (r * XP + (bd ? 65 : 0)) * CP + cg * 8) = z;
        }
    }
    __syncthreads();   // B3

    // ---------- conv2: wave = (rw = wave>>2, xq = wave&3) ----------
    {
        const int rw = wave >> 2, xq = wave & 3;
        const int n16 = lane & 15, quad = lane >> 4;
        f32x4 acc2 = {};
        const __bf16* aB = wA2 + n16 * 576 + quad * 8;
        #pragma unroll
        for (int dy = 0; dy < 3; ++dy)
            #pragma unroll
            for (int dx = 0; dx < 3; ++dx) {
                const int t9 = dy * 3 + dx;
                #pragma unroll
                for (int cq = 0; cq < 2; ++cq) {
                    bf16x8 a = *(const bf16x8*)(aB + t9 * 64 + cq * 32);
                    const __bf16* bp = sxo +
                        ((rw + dy) * XP + (xq * 16 + n16 + dx)) * CP + quad * 8 + cq * 32;
                    acc2 = __builtin_amdgcn_mfma_f32_16x16x32_bf16(
                        a, *(const bf16x8*)bp, acc2, 0, 0, 0);
                }
            }
        const int x = xq * 16 + n16;
        #pragma unroll
        for (int r = 0; r < 4; ++r) {
            int e = quad * 4 + r;
            float val = acc2[r] + attn_b[e];
            float sg = 1.f / (1.f + __expf(-val));
            attn_out[((size_t)(b * E + e) * H + (y0 + rw)) * W + x] = sg;
            s_attn[rw][x][e] = sg;   // disjoint region; no extra sync
        }
    }
    __syncthreads();   // B4

    // ---------- reduce: thread = (o = tid&63, eg = (tid>>6)&3, rr = tid>>8) --
    {
        const int o = tid & 63, eg = (tid >> 6) & 3, rr = tid >> 8;
        const float cb = c3_b[o];
        float accl[4] = {0.f, 0.f, 0.f, 0.f};
        const __bf16* spr = s_sp + (rr * 64 + o) * SPP;
        #pragma unroll 2
        for (int pb = 0; pb < 8; ++pb) {
            bf16x8 sp8 = *(const bf16x8*)(spr + pb * 8);
            #pragma unroll
            for (int k = 0; k < 8; ++k) {
                float spf = (float)sp8[k];
                f32x4 a4 = *(const f32x4*)&s_attn[rr][pb * 8 + k][eg * 4];
                #pragma unroll
                for (int i = 0; i < 4; ++i)
                    accl[i] += fmaxf(fmaf(a4[i], spf, cb), 0.f);
            }
        }
        const float border = (yp == 0 && rr == 0) ? 260.f * fmaxf(cb, 0.f) : 0.f;
        #pragma unroll
        for (int i = 0; i < 4; ++i) {
            int e = eg * 4 + i;
            atomicAdd(&out[(b * E + e) * F + o], (accl[i] + border) * (1.f / 4356.f));
        }
    }
}

// ---------------------------------------------------------------------------
extern "C" void kernel_launch(void* const* d_in, const int* in_sizes, int n_in,
                              void* d_out, int out_size, void* d_ws, size_t ws_size,
                              hipStream_t stream) {
    (void)in_sizes; (void)n_in; (void)out_size; (void)ws_size;
    const float* state  = (const float*)d_in[0];
    const float* pre_w  = (const float*)d_in[1];
    const float* pre_b  = (const float*)d_in[2];
    const float* attn_w = (const float*)d_in[3];
    const float* attn_b = (const float*)d_in[4];
    const float* c3_w   = (const float*)d_in[5];
    const float* c3_b   = (const float*)d_in[6];

    float* out      = (float*)d_out;
    float* attn_out = out + B * E * F;

    char* ws = (char*)d_ws;
    constexpr size_t XT_BYTES = (size_t)B * H * YSTRIDE * 2;   // 8,650,752
    __bf16* xTs  = (__bf16*)ws;
    __bf16* wA1  = (__bf16*)(ws + XT_BYTES);
    __bf16* wA2  = (__bf16*)(ws + XT_BYTES + 73728);
    __bf16* wT3b = (__bf16*)(ws + XT_BYTES + 73728 + 18432);

    prep_kernel<<<1184, 256, 0, stream>>>(state, pre_w, attn_w, c3_w,
                                          xTs, wA1, wA2, wT3b, out);
    mega_kernel<<<dim3(H / 2, B), 512, 0, stream>>>(xTs, wA1, wA2, wT3b,
                                                    pre_b, attn_b, c3_b,
                                                    attn_out, out);
}

// Round 13
// 130.777 us; speedup vs baseline: 1.0329x; 1.0329x over previous
//
#include <hip/hip_runtime.h>
#include <math.h>

constexpr int B = 16, F = 64, E = 16, H = 64, W = 64;
constexpr int XP = 66;          // padded x dim (1 zero col each side)
constexpr int CP = 72;          // s_in/sxo inner pad (16B-aligned bf16x8 rows)
constexpr int SPP = 68;         // s_sp inner pad (bf16)
constexpr int YSTRIDE = XP * F; // 4224 elems per (b,y) row in xTs

typedef __bf16 bf16x8 __attribute__((ext_vector_type(8)));
typedef __bf16 bf16x4 __attribute__((ext_vector_type(4)));
typedef float f32x16 __attribute__((ext_vector_type(16)));
typedef float f32x4 __attribute__((ext_vector_type(4)));

// ---------------------------------------------------------------------------
// prep: blk<1024: transpose state -> xTs[b][y][x+1][c] bf16 (borders zeroed)
//       blk<1168: repack weights (wA1[o][t*64+c], wA2[e][t*64+c], wT3b=bf16(c3_w))
//       else    : zero d_out[0..16383] (the (B,E,F) accumulator region)
// ---------------------------------------------------------------------------
__global__ __launch_bounds__(256) void prep_kernel(
    const float* __restrict__ state, const float* __restrict__ pre_w,
    const float* __restrict__ attn_w, const float* __restrict__ c3_w,
    __bf16* __restrict__ xTs, __bf16* __restrict__ wA1,
    __bf16* __restrict__ wA2, __bf16* __restrict__ wT3b,
    float* __restrict__ out0)
{
    __shared__ float s_t[64][68];
    const int blk = blockIdx.x;
    const int tid = threadIdx.x;

    if (blk < 1024) {
        const int b = blk >> 6, y = blk & 63;
        {
            int c = tid >> 2, x0 = (tid & 3) * 16;
            const float* src = state + ((size_t)(b * F + c) * H + y) * W + x0;
            #pragma unroll
            for (int q = 0; q < 4; ++q)
                *(float4*)&s_t[c][x0 + 4 * q] = *(const float4*)(src + 4 * q);
        }
        __syncthreads();
        __bf16* dst = xTs + (size_t)(b * H + y) * YSTRIDE;
        #pragma unroll
        for (int i = 0; i < 2; ++i) {
            int t = tid + i * 256;
            int x = t >> 3, cg = t & 7;
            bf16x8 v;
            #pragma unroll
            for (int j = 0; j < 8; ++j) v[j] = (__bf16)s_t[cg * 8 + j][x];
            *(bf16x8*)(dst + (x + 1) * F + cg * 8) = v;
        }
        if (tid < 16) {
            int bd = tid >> 3, cg = tid & 7;
            bf16x8 z = {};
            *(bf16x8*)(dst + (bd ? 65 : 0) * F + cg * 8) = z;
        }
    } else if (blk < 1168) {
        int idx = (blk - 1024) * 256 + tid;
        if (idx < 64 * 576) {
            int o = idx / 576, rem = idx - o * 576, t = rem >> 6, c = rem & 63;
            wA1[idx] = (__bf16)pre_w[(o * 64 + c) * 9 + t];
        }
        if (idx < 16 * 576) {
            int e = idx / 576, rem = idx - e * 576, t = rem >> 6, c = rem & 63;
            wA2[idx] = (__bf16)attn_w[(e * 64 + c) * 9 + t];
        }
        if (idx < 64 * 64) {
            wT3b[idx] = (__bf16)c3_w[idx];   // already [o][f] row-major
        }
    } else {
        int idx = (blk - 1168) * 256 + tid;  // 16 blocks cover 16384 floats
        float4 z = {0.f, 0.f, 0.f, 0.f};
        *(float4*)(out0 + idx * 4) = z;
    }
}

// ---------------------------------------------------------------------------
// mega v7: block = (b, single row y); 1024 blocks x 256 thr; LDS 47.5 KB
// -> 3 blocks/CU (12 waves/CU). 4 barriers:
//  stage rows y-2..y+2 | B1 | conv1 (wave=(mt,nt), 3 row-tiles, A-frags
//  hoisted) + sproj fused | B2 | epilogues -> sxo[3] + s_sp + borders | B3 |
//  conv2 (wave=x-quarter) -> sigmoid -> attn_out + s_attn | B4 |
//  reduce (thread=(o,eg)) -> atomicAdd out.
// ---------------------------------------------------------------------------
__global__ __launch_bounds__(256, 3) void mega_kernel(
    const __bf16* __restrict__ xTs, const __bf16* __restrict__ wA1,
    const __bf16* __restrict__ wA2, const __bf16* __restrict__ wT3b,
    const float* __restrict__ pre_b, const float* __restrict__ attn_b,
    const float* __restrict__ c3_b,
    float* __restrict__ attn_out, float* __restrict__ out)
{
    __shared__ __align__(16) char smem[47520];
    const int b = blockIdx.y, y = blockIdx.x;
    const int tid = threadIdx.x;
    const int wave = tid >> 6, lane = tid & 63;

    __bf16* s_in = (__bf16*)smem;                        // [5][XP][CP] 47520 B
    __bf16* sxo  = (__bf16*)smem;                        // [3][XP][CP] 28512 B (overlay)
    __bf16* s_sp = (__bf16*)(smem + 28512);              // [64][SPP]    8704 B
    float (*s_attn)[16] = (float(*)[16])(smem + 37216);  // [64][16]     4096 B

    // ---------- stage 5 input rows y-2..y+2 (coalesced; OOB rows zero) ------
    for (int t = tid; t < 5 * XP * 8; t += 256) {
        int r = t / (XP * 8), rem = t - r * (XP * 8);
        int x = rem >> 3, cg = rem & 7;
        int yy = y - 2 + r;
        bf16x8 v = {};
        if (yy >= 0 && yy < H)
            v = *(const bf16x8*)(xTs + (size_t)(b * H + yy) * YSTRIDE + x * F + cg * 8);
        *(bf16x8*)(s_in + (r * XP + x) * CP + cg * 8) = v;
    }
    __syncthreads();   // B1

    const int n = lane & 31, kh = lane >> 5;
    const int mt = wave >> 1, nt = wave & 1;

    // ---------- sproj fragment preload (row y; latency hides under conv1) ---
    bf16x8 spA[4], spB[4];
    #pragma unroll
    for (int cq = 0; cq < 4; ++cq) {
        spA[cq] = *(const bf16x8*)(wT3b + (mt * 32 + n) * 64 + kh * 8 + cq * 16);
        spB[cq] = *(const bf16x8*)(xTs + (size_t)(b * H + y) * YSTRIDE
                                   + (nt * 32 + n + 1) * F + kh * 8 + cq * 16);
    }

    // ---------- conv1: wave=(mt,nt) computes 3 output rows y-1..y+1 ----------
    f32x16 acc[3] = {};
    #pragma unroll
    for (int dy = 0; dy < 3; ++dy) {
        #pragma unroll
        for (int dx = 0; dx < 3; ++dx) {
            const int t9 = dy * 3 + dx;
            #pragma unroll
            for (int cq = 0; cq < 4; ++cq) {
                const int ko = cq * 16 + kh * 8;
                bf16x8 a = *(const bf16x8*)(wA1 + (mt * 32 + n) * 576 + t9 * 64 + ko);
                #pragma unroll
                for (int i = 0; i < 3; ++i) {
                    // output row y-1+i uses input row (y-1+i)-1+dy -> s_in row i+dy
                    const __bf16* bB = s_in + ((i + dy) * XP + (nt * 32 + n + dx)) * CP + ko;
                    acc[i] = __builtin_amdgcn_mfma_f32_32x32x16_bf16(
                        a, *(const bf16x8*)bB, acc[i], 0, 0, 0);
                }
            }
        }
    }

    // ---------- sproj MFMAs (fragments long since arrived) ----------
    f32x16 accsp = {};
    #pragma unroll
    for (int cq = 0; cq < 4; ++cq)
        accsp = __builtin_amdgcn_mfma_f32_32x32x16_bf16(spA[cq], spB[cq], accsp, 0, 0, 0);

    __syncthreads();   // B2: s_in dead; overlays writable

    // ---------- conv1 epilogue -> sxo[3]; sproj epilogue -> s_sp ----------
    {
        #pragma unroll
        for (int i = 0; i < 3; ++i) {
            const bool valid = ((unsigned)(y - 1 + i) < (unsigned)H);
            __bf16* orow = sxo + i * XP * CP;
            #pragma unroll
            for (int g = 0; g < 4; ++g) {
                int o0 = mt * 32 + kh * 4 + g * 8;
                f32x4 b4 = *(const f32x4*)(pre_b + o0);
                bf16x4 v0 = {};
                if (valid) {
                    #pragma unroll
                    for (int r = 0; r < 4; ++r)
                        v0[r] = (__bf16)fmaxf(acc[i][g * 4 + r] + b4[r], 0.f);
                }
                *(bf16x4*)(orow + (nt * 32 + n + 1) * CP + o0) = v0;
            }
        }
        // sproj: D row o = mt*32+kh*4+g*8+r, col p = nt*32+n
        const int p = nt * 32 + n;
        #pragma unroll
        for (int g = 0; g < 4; ++g)
            #pragma unroll
            for (int r = 0; r < 4; ++r) {
                int o = mt * 32 + kh * 4 + g * 8 + r;
                s_sp[o * SPP + p] = (__bf16)accsp[g * 4 + r];
            }
        if (tid < 48) {   // zero x-borders (cols 0 and 65) of the 3 sxo rows
            int r = tid >> 4, bd = (tid >> 3) & 1, cg = tid & 7;
            bf16x8 z = {};
            *(bf16x8*)(sxo + (r * XP + (bd ? 65 : 0)) * CP + cg * 8) = z;
        }
    }
    __syncthreads();   // B3

    // ---------- conv2: wave = x-quarter xq; output row y ----------
    {
        const int xq = wave;
        const int n16 = lane & 15, quad = lane >> 4;
        f32x4 acc2 = {};
        const __bf16* aB = wA2 + n16 * 576 + quad * 8;
        #pragma unroll
        for (int dy = 0; dy < 3; ++dy)
            #pragma unroll
            for (int dx = 0; dx < 3; ++dx) {
                const int t9 = dy * 3 + dx;
                #pragma unroll
                for (int cq = 0; cq < 2; ++cq) {
                    bf16x8 a = *(const bf16x8*)(aB + t9 * 64 + cq * 32);
                    const __bf16* bp = sxo +
                        (dy * XP + (xq * 16 + n16 + dx)) * CP + quad * 8 + cq * 32;
                    acc2 = __builtin_amdgcn_mfma_f32_16x16x32_bf16(
                        a, *(const bf16x8*)bp, acc2, 0, 0, 0);
                }
            }
        const int x = xq * 16 + n16;
        #pragma unroll
        for (int r = 0; r < 4; ++r) {
            int e = quad * 4 + r;
            float val = acc2[r] + attn_b[e];
            float sg = 1.f / (1.f + __expf(-val));
            attn_out[((size_t)(b * E + e) * H + y) * W + x] = sg;
            s_attn[x][e] = sg;   // disjoint region (dead s_in tail); no sync
        }
    }
    __syncthreads();   // B4

    // ---------- reduce: thread = (o = tid&63, eg = tid>>6) over 64 pixels ----
    {
        const int o = tid & 63, eg = tid >> 6;
        const float cb = c3_b[o];
        float accl[4] = {0.f, 0.f, 0.f, 0.f};
        const __bf16* spr = s_sp + o * SPP;
        #pragma unroll 2
        for (int pb = 0; pb < 8; ++pb) {
            bf16x8 sp8 = *(const bf16x8*)(spr + pb * 8);
            #pragma unroll
            for (int k = 0; k < 8; ++k) {
                float spf = (float)sp8[k];
                f32x4 a4 = *(const f32x4*)&s_attn[pb * 8 + k][eg * 4];
                #pragma unroll
                for (int i = 0; i < 4; ++i)
                    accl[i] += fmaxf(fmaf(a4[i], spf, cb), 0.f);
            }
        }
        const float border = (y == 0) ? 260.f * fmaxf(cb, 0.f) : 0.f;
        #pragma unroll
        for (int i = 0; i < 4; ++i) {
            int e = eg * 4 + i;
            atomicAdd(&out[(b * E + e) * F + o], (accl[i] + border) * (1.f / 4356.f));
        }
    }
}

// ---------------------------------------------------------------------------
extern "C" void kernel_launch(void* const* d_in, const int* in_sizes, int n_in,
                              void* d_out, int out_size, void* d_ws, size_t ws_size,
                              hipStream_t stream) {
    (void)in_sizes; (void)n_in; (void)out_size; (void)ws_size;
    const float* state  = (const float*)d_in[0];
    const float* pre_w  = (const float*)d_in[1];
    const float* pre_b  = (const float*)d_in[2];
    const float* attn_w = (const float*)d_in[3];
    const float* attn_b = (const float*)d_in[4];
    const float* c3_w   = (const float*)d_in[5];
    const float* c3_b   = (const float*)d_in[6];

    float* out      = (float*)d_out;
    float* attn_out = out + B * E * F;

    char* ws = (char*)d_ws;
    constexpr size_t XT_BYTES = (size_t)B * H * YSTRIDE * 2;   // 8,650,752
    __bf16* xTs  = (__bf16*)ws;
    __bf16* wA1  = (__bf16*)(ws + XT_BYTES);
    __bf16* wA2  = (__bf16*)(ws + XT_BYTES + 73728);
    __bf16* wT3b = (__bf16*)(ws + XT_BYTES + 73728 + 18432);

    prep_kernel<<<1184, 256, 0, stream>>>(state, pre_w, attn_w, c3_w,
                                          xTs, wA1, wA2, wT3b, out);
    mega_kernel<<<dim3(H, B), 256, 0, stream>>>(xTs, wA1, wA2, wT3b,
                                                pre_b, attn_b, c3_b,
                                                attn_out, out);
}

// Round 14
// 106.012 us; speedup vs baseline: 1.2742x; 1.2336x over previous
//
#include <hip/hip_runtime.h>
#include <math.h>

constexpr int B = 16, F = 64, E = 16, H = 64, W = 64;
constexpr int XP = 66;          // padded x dim (1 zero col each side)
constexpr int CP = 72;          // s_in/sxo inner pad (16B-aligned bf16x8 rows)
constexpr int SPP = 68;         // s_sp inner pad (bf16)
constexpr int YSTRIDE = XP * F; // 4224 elems per (b,y) row in xTs

typedef __bf16 bf16x8 __attribute__((ext_vector_type(8)));
typedef __bf16 bf16x4 __attribute__((ext_vector_type(4)));
typedef float f32x16 __attribute__((ext_vector_type(16)));
typedef float f32x4 __attribute__((ext_vector_type(4)));

// ---------------------------------------------------------------------------
// prep: blk<1024: transpose state -> xTs[b][y][x+1][c] bf16 (borders zeroed)
//       blk<1168: repack weights into FRAGMENT-MAJOR layouts so MFMA A-loads
//                 are wave-contiguous (8 cache lines/instr instead of 64):
//         wA1f[t9][cq][mt][kh][n][8]  = pre_w[o=mt*32+n][c=cq*16+kh*8+j][t9]
//         wA2f[t9][cq][quad][n16][8]  = attn_w[e=n16][c=cq*32+quad*8+j][t9]
//         wT3bf[cq][mt][kh][n][8]     = c3_w[o=mt*32+n][f=cq*16+kh*8+j]
//       else    : zero d_out[0..16383] (the (B,E,F) accumulator region)
// ---------------------------------------------------------------------------
__global__ __launch_bounds__(256) void prep_kernel(
    const float* __restrict__ state, const float* __restrict__ pre_w,
    const float* __restrict__ attn_w, const float* __restrict__ c3_w,
    __bf16* __restrict__ xTs, __bf16* __restrict__ wA1f,
    __bf16* __restrict__ wA2f, __bf16* __restrict__ wT3bf,
    float* __restrict__ out0)
{
    __shared__ float s_t[64][68];
    const int blk = blockIdx.x;
    const int tid = threadIdx.x;

    if (blk < 1024) {
        const int b = blk >> 6, y = blk & 63;
        {
            int c = tid >> 2, x0 = (tid & 3) * 16;
            const float* src = state + ((size_t)(b * F + c) * H + y) * W + x0;
            #pragma unroll
            for (int q = 0; q < 4; ++q)
                *(float4*)&s_t[c][x0 + 4 * q] = *(const float4*)(src + 4 * q);
        }
        __syncthreads();
        __bf16* dst = xTs + (size_t)(b * H + y) * YSTRIDE;
        #pragma unroll
        for (int i = 0; i < 2; ++i) {
            int t = tid + i * 256;
            int x = t >> 3, cg = t & 7;
            bf16x8 v;
            #pragma unroll
            for (int j = 0; j < 8; ++j) v[j] = (__bf16)s_t[cg * 8 + j][x];
            *(bf16x8*)(dst + (x + 1) * F + cg * 8) = v;
        }
        if (tid < 16) {
            int bd = tid >> 3, cg = tid & 7;
            bf16x8 z = {};
            *(bf16x8*)(dst + (bd ? 65 : 0) * F + cg * 8) = z;
        }
    } else if (blk < 1168) {
        int idx = (blk - 1024) * 256 + tid;
        {   // wA1f: 36864 elems exactly (144 blocks x 256)
            int j = idx & 7, n = (idx >> 3) & 31, kh = (idx >> 8) & 1;
            int mt = (idx >> 9) & 1, cq = (idx >> 10) & 3, t9 = idx >> 12;
            int o = mt * 32 + n, c = cq * 16 + kh * 8 + j;
            wA1f[idx] = (__bf16)pre_w[(o * 64 + c) * 9 + t9];
        }
        if (idx < 9216) {  // wA2f
            int j = idx & 7, n16 = (idx >> 3) & 15, quad = (idx >> 7) & 3;
            int cq = (idx >> 9) & 1, t9 = idx >> 10;
            int c = cq * 32 + quad * 8 + j;
            wA2f[idx] = (__bf16)attn_w[(n16 * 64 + c) * 9 + t9];
        }
        if (idx < 4096) {  // wT3bf
            int j = idx & 7, n = (idx >> 3) & 31, kh = (idx >> 8) & 1;
            int mt = (idx >> 9) & 1, cq = idx >> 10;
            wT3bf[idx] = (__bf16)c3_w[(mt * 32 + n) * 64 + cq * 16 + kh * 8 + j];
        }
    } else {
        int idx = (blk - 1168) * 256 + tid;  // 16 blocks cover 16384 floats
        float4 z = {0.f, 0.f, 0.f, 0.f};
        *(float4*)(out0 + idx * 4) = z;
    }
}

// ---------------------------------------------------------------------------
// mega v8 = R11 structure + fragment-major weights + sproj-B from LDS.
// 4 barriers:
//  stage s_in (6 rows) | B1 | conv1 (wave=row, M64xN64) + sproj (B from s_in
//  rows 2,3) | B2 | epilogues -> sxo + s_sp + borders | B3 | conv2 -> sigmoid
//  -> attn_out + s_attn | B4 | reduce (thread=(o,eg)) -> atomicAdd.
// ---------------------------------------------------------------------------
__global__ __launch_bounds__(256, 2) void mega_kernel(
    const __bf16* __restrict__ xTs, const __bf16* __restrict__ wA1f,
    const __bf16* __restrict__ wA2f, const __bf16* __restrict__ wT3bf,
    const float* __restrict__ pre_b, const float* __restrict__ attn_b,
    const float* __restrict__ c3_b,
    float* __restrict__ attn_out, float* __restrict__ out)
{
    __shared__ __align__(16) char smem[63616];
    const int b = blockIdx.y, yp = blockIdx.x;
    const int tid = threadIdx.x;
    const int wave = tid >> 6, lane = tid & 63;
    const int y0 = yp * 2;

    __bf16* s_in = (__bf16*)smem;                        // [6][XP][CP] 57024 B
    __bf16* sxo  = (__bf16*)smem;                        // [4][XP][CP] 38016 B (overlay)
    __bf16* s_sp = (__bf16*)(smem + 38016);              // [2][64][SPP] 17408 B
    float (*s_attn)[64][16] = (float(*)[64][16])(smem + 55424);  // 8192 B

    // ---------- stage 6 input rows (coalesced; OOB rows zero) ----------
    for (int t = tid; t < 6 * XP * 8; t += 256) {
        int r = t / (XP * 8), rem = t - r * (XP * 8);
        int x = rem >> 3, cg = rem & 7;
        int yy = y0 - 2 + r;
        bf16x8 v = {};
        if (yy >= 0 && yy < H)
            v = *(const bf16x8*)(xTs + (size_t)(b * H + yy) * YSTRIDE + x * F + cg * 8);
        *(bf16x8*)(s_in + (r * XP + x) * CP + cg * 8) = v;
    }
    __syncthreads();   // B1

    const int n = lane & 31, kh = lane >> 5;
    const int mt = wave & 1, nt = wave >> 1;   // sproj tile mapping (per R11)

    // ---------- sproj A preload (coalesced fragment-major; tiny) ----------
    bf16x8 spA[4];
    #pragma unroll
    for (int cq = 0; cq < 4; ++cq)
        spA[cq] = *(const bf16x8*)(wT3bf + cq * 1024 + mt * 512 + kh * 256 + n * 8);

    // ---------- conv1: wave -> output row yr = y0-1+wave ----------
    const int yr = y0 - 1 + wave;
    const bool valid = (yr >= 0 && yr < H);
    f32x16 acc[4] = {};   // [mt2*2+nt2] tiles of the 64x64 output
    if (valid) {
        #pragma unroll
        for (int dy = 0; dy < 3; ++dy) {
            // input row in s_in: (yr-1+dy) - (y0-2) = wave + dy
            #pragma unroll
            for (int dx = 0; dx < 3; ++dx) {
                const int t9 = dy * 3 + dx;
                const __bf16* bB = s_in + ((wave + dy) * XP + (n + dx)) * CP + kh * 8;
                const __bf16* aB = wA1f + t9 * 4096 + kh * 256 + n * 8;
                #pragma unroll
                for (int cq = 0; cq < 4; ++cq) {
                    bf16x8 a0 = *(const bf16x8*)(aB + cq * 1024);          // mt=0
                    bf16x8 a1 = *(const bf16x8*)(aB + cq * 1024 + 512);    // mt=1
                    bf16x8 b0 = *(const bf16x8*)(bB + cq * 16);
                    bf16x8 b1 = *(const bf16x8*)(bB + 32 * CP + cq * 16);
                    acc[0] = __builtin_amdgcn_mfma_f32_32x32x16_bf16(a0, b0, acc[0], 0, 0, 0);
                    acc[1] = __builtin_amdgcn_mfma_f32_32x32x16_bf16(a0, b1, acc[1], 0, 0, 0);
                    acc[2] = __builtin_amdgcn_mfma_f32_32x32x16_bf16(a1, b0, acc[2], 0, 0, 0);
                    acc[3] = __builtin_amdgcn_mfma_f32_32x32x16_bf16(a1, b1, acc[3], 0, 0, 0);
                }
            }
        }
    }

    // ---------- sproj MFMAs: B-fragments from s_in rows 2,3 (= rows y0,y0+1) --
    f32x16 accsp[2] = {};
    #pragma unroll
    for (int rr = 0; rr < 2; ++rr)
        #pragma unroll
        for (int cq = 0; cq < 4; ++cq) {
            bf16x8 bb = *(const bf16x8*)(s_in + ((2 + rr) * XP + nt * 32 + n + 1) * CP
                                         + cq * 16 + kh * 8);
            accsp[rr] = __builtin_amdgcn_mfma_f32_32x32x16_bf16(spA[cq], bb, accsp[rr], 0, 0, 0);
        }

    __syncthreads();   // B2: all s_in reads done; overlays writable

    // ---------- conv1 epilogue -> sxo; sproj epilogue -> s_sp ----------
    {
        __bf16* orow = sxo + wave * XP * CP;
        #pragma unroll
        for (int mt2 = 0; mt2 < 2; ++mt2)
            #pragma unroll
            for (int g = 0; g < 4; ++g) {
                int o0 = mt2 * 32 + kh * 4 + g * 8;
                f32x4 b4 = *(const f32x4*)(pre_b + o0);
                bf16x4 v0 = {}, v1 = {};
                if (valid) {
                    #pragma unroll
                    for (int r = 0; r < 4; ++r) {
                        v0[r] = (__bf16)fmaxf(acc[mt2 * 2 + 0][g * 4 + r] + b4[r], 0.f);
                        v1[r] = (__bf16)fmaxf(acc[mt2 * 2 + 1][g * 4 + r] + b4[r], 0.f);
                    }
                }
                *(bf16x4*)(orow + (n + 1) * CP + o0) = v0;
                *(bf16x4*)(orow + (n + 33) * CP + o0) = v1;
            }
        // sproj: D row o = mt*32+kh*4+g*8+r, col p = nt*32+n
        const int p = nt * 32 + n;
        #pragma unroll
        for (int rr = 0; rr < 2; ++rr)
            #pragma unroll
            for (int g = 0; g < 4; ++g)
                #pragma unroll
                for (int r = 0; r < 4; ++r) {
                    int o = mt * 32 + kh * 4 + g * 8 + r;
                    s_sp[(rr * 64 + o) * SPP + p] = (__bf16)accsp[rr][g * 4 + r];
                }
        if (tid < 64) {   // zero x-borders (cols 0 and 65) of all 4 sxo rows
            int r = tid >> 4, bd = (tid >> 3) & 1, cg = tid & 7;
            bf16x8 z = {};
            *(bf16x8*)(sxo + (r * XP + (bd ? 65 : 0)) * CP + cg * 8) = z;
        }
    }
    __syncthreads();   // B3

    // ---------- conv2: wave = (row rw, x-half nt2) ----------
    {
        const int rw = wave >> 1, nt2 = wave & 1;
        const int n16 = lane & 15, quad = lane >> 4;
        f32x4 acc2[2] = {};
        #pragma unroll
        for (int dy = 0; dy < 3; ++dy)
            #pragma unroll
            for (int dx = 0; dx < 3; ++dx) {
                const int t9 = dy * 3 + dx;
                #pragma unroll
                for (int cq = 0; cq < 2; ++cq) {
                    bf16x8 a = *(const bf16x8*)(wA2f + ((t9 * 2 + cq) * 4 + quad) * 128
                                                + n16 * 8);
                    #pragma unroll
                    for (int i = 0; i < 2; ++i) {
                        const __bf16* bp = sxo +
                            ((rw + dy) * XP + (nt2 * 32 + i * 16 + n16 + dx)) * CP
                            + quad * 8 + cq * 32;
                        acc2[i] = __builtin_amdgcn_mfma_f32_16x16x32_bf16(
                            a, *(const bf16x8*)bp, acc2[i], 0, 0, 0);
                    }
                }
            }
        #pragma unroll
        for (int i = 0; i < 2; ++i) {
            int x = nt2 * 32 + i * 16 + n16;
            #pragma unroll
            for (int r = 0; r < 4; ++r) {
                int e = quad * 4 + r;
                float val = acc2[i][r] + attn_b[e];
                float sg = 1.f / (1.f + __expf(-val));
                attn_out[((size_t)(b * E + e) * H + (y0 + rw)) * W + x] = sg;
                s_attn[rw][x][e] = sg;   // disjoint region; no extra sync
            }
        }
    }
    __syncthreads();   // B4

    // ---------- reduce: thread = (o = tid&63, eg = tid>>6) ----------
    {
        const int o = tid & 63, eg = tid >> 6;
        const float cb = c3_b[o];
        float accl[4] = {0.f, 0.f, 0.f, 0.f};
        #pragma unroll
        for (int rr = 0; rr < 2; ++rr) {
            const __bf16* spr = s_sp + (rr * 64 + o) * SPP;
            #pragma unroll 2
            for (int pb = 0; pb < 8; ++pb) {
                bf16x8 sp8 = *(const bf16x8*)(spr + pb * 8);
                #pragma unroll
                for (int k = 0; k < 8; ++k) {
                    float spf = (float)sp8[k];
                    f32x4 a4 = *(const f32x4*)&s_attn[rr][pb * 8 + k][eg * 4];
                    #pragma unroll
                    for (int i = 0; i < 4; ++i)
                        accl[i] += fmaxf(fmaf(a4[i], spf, cb), 0.f);
                }
            }
        }
        const float border = (yp == 0) ? 260.f * fmaxf(cb, 0.f) : 0.f;
        #pragma unroll
        for (int i = 0; i < 4; ++i) {
            int e = eg * 4 + i;
            atomicAdd(&out[(b * E + e) * F + o], (accl[i] + border) * (1.f / 4356.f));
        }
    }
}

// ---------------------------------------------------------------------------
extern "C" void kernel_launch(void* const* d_in, const int* in_sizes, int n_in,
                              void* d_out, int out_size, void* d_ws, size_t ws_size,
                              hipStream_t stream) {
    (void)in_sizes; (void)n_in; (void)out_size; (void)ws_size;
    const float* state  = (const float*)d_in[0];
    const float* pre_w  = (const float*)d_in[1];
    const float* pre_b  = (const float*)d_in[2];
    const float* attn_w = (const float*)d_in[3];
    const float* attn_b = (const float*)d_in[4];
    const float* c3_w   = (const float*)d_in[5];
    const float* c3_b   = (const float*)d_in[6];

    float* out      = (float*)d_out;
    float* attn_out = out + B * E * F;

    char* ws = (char*)d_ws;
    constexpr size_t XT_BYTES = (size_t)B * H * YSTRIDE * 2;   // 8,650,752
    __bf16* xTs   = (__bf16*)ws;
    __bf16* wA1f  = (__bf16*)(ws + XT_BYTES);
    __bf16* wA2f  = (__bf16*)(ws + XT_BYTES + 73728);
    __bf16* wT3bf = (__bf16*)(ws + XT_BYTES + 73728 + 18432);

    prep_kernel<<<1184, 256, 0, stream>>>(state, pre_w, attn_w, c3_w,
                                          xTs, wA1f, wA2f, wT3bf, out);
    mega_kernel<<<dim3(H / 2, B), 256, 0, stream>>>(xTs, wA1f, wA2f, wT3bf,
                                                    pre_b, attn_b, c3_b,
                                                    attn_out, out);
}